// Round 6
// baseline (167.603 us; speedup 1.0000x reference)
//
#include <hip/hip_runtime.h>
#include <math.h>

#define B_ 4096
#define K_ 64
#define D_ 128
#define FXSCALE 1099511627776.0   // 2^40, fixed-point scale for deterministic int reduction

__global__ __launch_bounds__(256) void bpr_fused(
    const int* __restrict__ user, const int* __restrict__ pos,
    const int* __restrict__ negs, const float* __restrict__ uemb,
    const float* __restrict__ iemb,
    unsigned long long* __restrict__ acc,   // acc[0]=loss_fx, acc[1]=reg_fx, acc[2]=counter
    float* __restrict__ out)
{
    const int b    = blockIdx.x;
    const int tid  = threadIdx.x;
    const int lane = tid & 63;
    const int wave = tid >> 6;
    const int g    = lane >> 3;   // 8-lane group id (0..7) -> which neg row
    const int s    = lane & 7;    // position in group -> which 64B chunk

    __shared__ float s_scores[K_];
    __shared__ float s_pos[3];     // dot_pos, sq_pos, sq_u
    __shared__ int   s_last;

    // u chunk for this lane: 16 contiguous floats at s*16 (groups redundant, coalesced to 512B)
    const float* urow = uemb + (size_t)user[b] * D_;
    const float4 u0 = *reinterpret_cast<const float4*>(urow + s * 16 + 0);
    const float4 u1 = *reinterpret_cast<const float4*>(urow + s * 16 + 4);
    const float4 u2 = *reinterpret_cast<const float4*>(urow + s * 16 + 8);
    const float4 u3 = *reinterpret_cast<const float4*>(urow + s * 16 + 12);

    const int* nrow = negs + (size_t)b * K_;
    const int k0 = wave * 16 + g;
    const int k1 = k0 + 8;
    const float* nra = iemb + (size_t)nrow[k0] * D_ + s * 16;
    const float* nrb = iemb + (size_t)nrow[k1] * D_ + s * 16;

    // issue all 8 row loads back-to-back (max MLP)
    const float4 a0 = *reinterpret_cast<const float4*>(nra + 0);
    const float4 a1 = *reinterpret_cast<const float4*>(nra + 4);
    const float4 a2 = *reinterpret_cast<const float4*>(nra + 8);
    const float4 a3 = *reinterpret_cast<const float4*>(nra + 12);
    const float4 b0 = *reinterpret_cast<const float4*>(nrb + 0);
    const float4 b1 = *reinterpret_cast<const float4*>(nrb + 4);
    const float4 b2 = *reinterpret_cast<const float4*>(nrb + 8);
    const float4 b3 = *reinterpret_cast<const float4*>(nrb + 12);

    float dotA = (a0.x*u0.x + a0.y*u0.y + a0.z*u0.z + a0.w*u0.w)
               + (a1.x*u1.x + a1.y*u1.y + a1.z*u1.z + a1.w*u1.w)
               + (a2.x*u2.x + a2.y*u2.y + a2.z*u2.z + a2.w*u2.w)
               + (a3.x*u3.x + a3.y*u3.y + a3.z*u3.z + a3.w*u3.w);
    float dotB = (b0.x*u0.x + b0.y*u0.y + b0.z*u0.z + b0.w*u0.w)
               + (b1.x*u1.x + b1.y*u1.y + b1.z*u1.z + b1.w*u1.w)
               + (b2.x*u2.x + b2.y*u2.y + b2.z*u2.z + b2.w*u2.w)
               + (b3.x*u3.x + b3.y*u3.y + b3.z*u3.z + b3.w*u3.w);

    #pragma unroll
    for (int off = 4; off; off >>= 1) {     // stays within 8-lane group
        dotA += __shfl_xor(dotA, off);
        dotB += __shfl_xor(dotB, off);
    }
    if (s == 0) { s_scores[k0] = dotA; s_scores[k1] = dotB; }

    // wave 0 extra: half0 -> pos dot + pos sq ; half1 -> u sq (32-lane float4 path)
    if (wave == 0) {
        const int half = lane >> 5, sub = lane & 31;
        const float4 uv = *reinterpret_cast<const float4*>(urow + sub * 4);
        const float4 pv = *reinterpret_cast<const float4*>(
            iemb + (size_t)pos[b] * D_ + sub * 4);
        float a = half ? (uv.x*uv.x + uv.y*uv.y + uv.z*uv.z + uv.w*uv.w)
                       : (uv.x*pv.x + uv.y*pv.y + uv.z*pv.z + uv.w*pv.w);
        float c = pv.x*pv.x + pv.y*pv.y + pv.z*pv.z + pv.w*pv.w;
        #pragma unroll
        for (int off = 16; off; off >>= 1) {
            a += __shfl_xor(a, off);
            c += __shfl_xor(c, off);
        }
        if (lane == 0)  { s_pos[0] = a; s_pos[1] = c; }
        if (lane == 32) { s_pos[2] = a; }
    }
    __syncthreads();

    if (wave == 0) {
        // parallel first-occurrence argmax over 64 scores
        float v  = s_scores[lane];
        int  idx = lane;
        #pragma unroll
        for (int off = 32; off; off >>= 1) {
            const float ov = __shfl_xor(v, off);
            const int   oi = __shfl_xor(idx, off);
            if (ov > v || (ov == v && oi < idx)) { v = ov; idx = oi; }
        }
        // square-sum of the chosen negative row (L1-hot reload)
        const int nidx = nrow[idx];
        const float2 nv2 = *reinterpret_cast<const float2*>(
            iemb + (size_t)nidx * D_ + lane * 2);
        float sqn = nv2.x * nv2.x + nv2.y * nv2.y;
        #pragma unroll
        for (int off = 32; off; off >>= 1)
            sqn += __shfl_xor(sqn, off);
        if (lane == 0) {
            const float diff = s_pos[0] - v;   // pos_score - neg_score
            const float li = (diff >= 0.f) ? log1pf(expf(-diff))
                                           : (-diff + log1pf(expf(diff)));
            const float regp = s_pos[2] + s_pos[1] + sqn;
            // fixed-point partials: integer atomics are commutative -> bit-deterministic.
            // Values travel through the coherent atomic point; NO fence / L2 writeback needed.
            const unsigned long long lfx = (unsigned long long)((double)li   * FXSCALE);
            const unsigned long long rfx = (unsigned long long)((double)regp * FXSCALE);
            atomicAdd(&acc[0], lfx);
            atomicAdd(&acc[1], rfx);
            // wait for the atomic acks (commit at coherence point) before the counter bump;
            // plain waitcnt, not a cache-maintenance fence (round-4 lesson).
            asm volatile("s_waitcnt vmcnt(0)" ::: "memory");
            const unsigned old = atomicAdd((unsigned*)&acc[2], 1u);
            s_last = (old == (unsigned)(gridDim.x - 1));
        }
    }
    __syncthreads();

    if (tid == 0 && s_last) {
        const unsigned long long Lf =
            __hip_atomic_load(&acc[0], __ATOMIC_RELAXED, __HIP_MEMORY_SCOPE_AGENT);
        const unsigned long long Rf =
            __hip_atomic_load(&acc[1], __ATOMIC_RELAXED, __HIP_MEMORY_SCOPE_AGENT);
        out[0] = (float)((double)Lf / FXSCALE / (double)B_);
        out[1] = (float)(1e-5 * 0.5 * (double)Rf / FXSCALE / (double)B_);
    }
}

extern "C" void kernel_launch(void* const* d_in, const int* in_sizes, int n_in,
                              void* d_out, int out_size, void* d_ws, size_t ws_size,
                              hipStream_t stream) {
    const int*   user = (const int*)  d_in[0];
    const int*   pos  = (const int*)  d_in[1];
    const int*   negs = (const int*)  d_in[2];
    const float* uemb = (const float*)d_in[3];
    const float* iemb = (const float*)d_in[4];
    float*              out = (float*)d_out;
    unsigned long long* acc = (unsigned long long*)d_ws;

    hipMemsetAsync(acc, 0, 3 * sizeof(unsigned long long), stream);  // graph-capturable
    bpr_fused<<<B_, 256, 0, stream>>>(user, pos, negs, uemb, iemb, acc, out);
}

// Round 7
// 35.104 us; speedup vs baseline: 4.7744x; 4.7744x over previous
//
#include <hip/hip_runtime.h>
#include <math.h>

#define B_ 4096
#define K_ 64
#define D_ 128
#define NSLOT 64
#define FXSCALE 1099511627776.0   // 2^40 fixed-point scale (deterministic int reduction)

struct __align__(64) Slot {                 // one 64B cache line per slot
    unsigned long long loss, reg, cnt, pad[5];
};

__global__ __launch_bounds__(256) void bpr_fused(
    const int* __restrict__ user, const int* __restrict__ pos,
    const int* __restrict__ negs, const float* __restrict__ uemb,
    const float* __restrict__ iemb,
    Slot* __restrict__ slots, unsigned long long* __restrict__ cnt2,
    float* __restrict__ out)
{
    const int b    = blockIdx.x;
    const int tid  = threadIdx.x;
    const int lane = tid & 63;
    const int wave = tid >> 6;
    const int g    = lane >> 3;   // 8-lane group id (0..7) -> which neg row
    const int s    = lane & 7;    // position in group -> which 64B chunk

    __shared__ float s_scores[K_];
    __shared__ float s_pos[3];     // dot_pos, sq_pos, sq_u
    __shared__ int   s_last;

    // u chunk for this lane: 16 contiguous floats at s*16 (groups redundant, coalesced)
    const float* urow = uemb + (size_t)user[b] * D_;
    const float4 u0 = *reinterpret_cast<const float4*>(urow + s * 16 + 0);
    const float4 u1 = *reinterpret_cast<const float4*>(urow + s * 16 + 4);
    const float4 u2 = *reinterpret_cast<const float4*>(urow + s * 16 + 8);
    const float4 u3 = *reinterpret_cast<const float4*>(urow + s * 16 + 12);

    const int* nrow = negs + (size_t)b * K_;
    const int k0 = wave * 16 + g;
    const int k1 = k0 + 8;
    const float* nra = iemb + (size_t)nrow[k0] * D_ + s * 16;
    const float* nrb = iemb + (size_t)nrow[k1] * D_ + s * 16;

    // issue all 8 row loads back-to-back (max MLP)
    const float4 a0 = *reinterpret_cast<const float4*>(nra + 0);
    const float4 a1 = *reinterpret_cast<const float4*>(nra + 4);
    const float4 a2 = *reinterpret_cast<const float4*>(nra + 8);
    const float4 a3 = *reinterpret_cast<const float4*>(nra + 12);
    const float4 b0 = *reinterpret_cast<const float4*>(nrb + 0);
    const float4 b1 = *reinterpret_cast<const float4*>(nrb + 4);
    const float4 b2 = *reinterpret_cast<const float4*>(nrb + 8);
    const float4 b3 = *reinterpret_cast<const float4*>(nrb + 12);

    float dotA = (a0.x*u0.x + a0.y*u0.y + a0.z*u0.z + a0.w*u0.w)
               + (a1.x*u1.x + a1.y*u1.y + a1.z*u1.z + a1.w*u1.w)
               + (a2.x*u2.x + a2.y*u2.y + a2.z*u2.z + a2.w*u2.w)
               + (a3.x*u3.x + a3.y*u3.y + a3.z*u3.z + a3.w*u3.w);
    float dotB = (b0.x*u0.x + b0.y*u0.y + b0.z*u0.z + b0.w*u0.w)
               + (b1.x*u1.x + b1.y*u1.y + b1.z*u1.z + b1.w*u1.w)
               + (b2.x*u2.x + b2.y*u2.y + b2.z*u2.z + b2.w*u2.w)
               + (b3.x*u3.x + b3.y*u3.y + b3.z*u3.z + b3.w*u3.w);

    #pragma unroll
    for (int off = 4; off; off >>= 1) {     // stays within 8-lane group
        dotA += __shfl_xor(dotA, off);
        dotB += __shfl_xor(dotB, off);
    }
    if (s == 0) { s_scores[k0] = dotA; s_scores[k1] = dotB; }

    // wave 0 extra: half0 -> pos dot + pos sq ; half1 -> u sq (32-lane float4 path)
    if (wave == 0) {
        const int half = lane >> 5, sub = lane & 31;
        const float4 uv = *reinterpret_cast<const float4*>(urow + sub * 4);
        const float4 pv = *reinterpret_cast<const float4*>(
            iemb + (size_t)pos[b] * D_ + sub * 4);
        float a = half ? (uv.x*uv.x + uv.y*uv.y + uv.z*uv.z + uv.w*uv.w)
                       : (uv.x*pv.x + uv.y*pv.y + uv.z*pv.z + uv.w*pv.w);
        float c = pv.x*pv.x + pv.y*pv.y + pv.z*pv.z + pv.w*pv.w;
        #pragma unroll
        for (int off = 16; off; off >>= 1) {
            a += __shfl_xor(a, off);
            c += __shfl_xor(c, off);
        }
        if (lane == 0)  { s_pos[0] = a; s_pos[1] = c; }
        if (lane == 32) { s_pos[2] = a; }
    }
    __syncthreads();

    if (wave == 0) {
        // parallel first-occurrence argmax over 64 scores
        float v  = s_scores[lane];
        int  idx = lane;
        #pragma unroll
        for (int off = 32; off; off >>= 1) {
            const float ov = __shfl_xor(v, off);
            const int   oi = __shfl_xor(idx, off);
            if (ov > v || (ov == v && oi < idx)) { v = ov; idx = oi; }
        }
        // square-sum of the chosen negative row (L1-hot reload)
        const int nidx = nrow[idx];
        const float2 nv2 = *reinterpret_cast<const float2*>(
            iemb + (size_t)nidx * D_ + lane * 2);
        float sqn = nv2.x * nv2.x + nv2.y * nv2.y;
        #pragma unroll
        for (int off = 32; off; off >>= 1)
            sqn += __shfl_xor(sqn, off);
        if (lane == 0) {
            const float diff = s_pos[0] - v;   // pos_score - neg_score
            const float li = (diff >= 0.f) ? log1pf(expf(-diff))
                                           : (-diff + log1pf(expf(diff)));
            const float regp = s_pos[2] + s_pos[1] + sqn;
            const unsigned long long lfx = (unsigned long long)((double)li   * FXSCALE);
            const unsigned long long rfx = (unsigned long long)((double)regp * FXSCALE);

            // contention-spread accumulation: slot (b&63) = private 64B line
            Slot* sl = &slots[b & (NSLOT - 1)];
            atomicAdd(&sl->loss, lfx);
            atomicAdd(&sl->reg,  rfx);
            asm volatile("s_waitcnt vmcnt(0)" ::: "memory");   // value adds at coherence pt
            const unsigned long long o1 = atomicAdd(&sl->cnt, 1ull);
            int fin = 0;
            if (o1 == (unsigned long long)(B_ / NSLOT - 1)) {  // slot closer
                asm volatile("s_waitcnt vmcnt(0)" ::: "memory");
                const unsigned long long o2 = atomicAdd(cnt2, 1ull);
                fin = (o2 == (unsigned long long)(NSLOT - 1)); // last closer -> reducer
            }
            s_last = fin;
        }
    }
    __syncthreads();

    if (s_last && wave == 0) {
        // lane i reads slot i from the coherence point; 64-wide shuffle reduce
        unsigned long long Lf = __hip_atomic_load(
            &slots[lane].loss, __ATOMIC_RELAXED, __HIP_MEMORY_SCOPE_AGENT);
        unsigned long long Rf = __hip_atomic_load(
            &slots[lane].reg,  __ATOMIC_RELAXED, __HIP_MEMORY_SCOPE_AGENT);
        #pragma unroll
        for (int off = 32; off; off >>= 1) {
            Lf += __shfl_xor(Lf, off);
            Rf += __shfl_xor(Rf, off);
        }
        if (lane == 0) {
            out[0] = (float)((double)Lf / FXSCALE / (double)B_);
            out[1] = (float)(1e-5 * 0.5 * (double)Rf / FXSCALE / (double)B_);
        }
    }
}

extern "C" void kernel_launch(void* const* d_in, const int* in_sizes, int n_in,
                              void* d_out, int out_size, void* d_ws, size_t ws_size,
                              hipStream_t stream) {
    const int*   user = (const int*)  d_in[0];
    const int*   pos  = (const int*)  d_in[1];
    const int*   negs = (const int*)  d_in[2];
    const float* uemb = (const float*)d_in[3];
    const float* iemb = (const float*)d_in[4];
    float* out = (float*)d_out;

    Slot*               slots = (Slot*)d_ws;
    unsigned long long* cnt2  = (unsigned long long*)((char*)d_ws + NSLOT * sizeof(Slot));

    hipMemsetAsync(d_ws, 0, NSLOT * sizeof(Slot) + 64, stream);  // graph-capturable
    bpr_fused<<<B_, 256, 0, stream>>>(user, pos, negs, uemb, iemb, slots, cnt2, out);
}